// Round 3
// baseline (2611.252 us; speedup 1.0000x reference)
//
#include <hip/hip_runtime.h>

// ---------------- problem constants ----------------
namespace {
constexpr int NN  = 50000;    // nodes
constexpr int FF  = 128;      // in features
constexpr int EE  = 1600000;  // edges
constexpr int HID = 256;      // hidden
constexpr int GG  = 512;      // graphs
constexpr int CC  = 10;       // classes
}

// ---------------- small utility kernels ----------------

__global__ __launch_bounds__(256) void k_zero_out(float* p, int n) {
    int i = blockIdx.x * 256 + threadIdx.x;
    if (i < n) p[i] = 0.0f;
}

__global__ __launch_bounds__(256) void k_fill_int(int* p, int val, int n) {
    int i = blockIdx.x * 256 + threadIdx.x;
    if (i < n) p[i] = val;
}

__global__ __launch_bounds__(256) void k_count(const int* __restrict__ dst,
                                               int* __restrict__ deg, int n) {
    int i = blockIdx.x * 256 + threadIdx.x;
    if (i < n) atomicAdd(&deg[dst[i]], 1);
}

__global__ __launch_bounds__(256) void k_dinv(const int* __restrict__ deg,
                                              float* __restrict__ dinv, int n) {
    int i = blockIdx.x * 256 + threadIdx.x;
    if (i < n) dinv[i] = 1.0f / sqrtf((float)deg[i]);
}

// exclusive scan of (deg[i]-1) -> rowstart ; per-block totals -> bsum
__global__ __launch_bounds__(256) void k_scan1(const int* __restrict__ deg,
                                               int* __restrict__ rowstart,
                                               int* __restrict__ bsum, int n) {
    __shared__ int s[256];
    int tid = threadIdx.x;
    int i = blockIdx.x * 256 + tid;
    int v = (i < n) ? (deg[i] - 1) : 0;
    s[tid] = v;
    __syncthreads();
    for (int off = 1; off < 256; off <<= 1) {
        int t = (tid >= off) ? s[tid - off] : 0;
        __syncthreads();
        s[tid] += t;
        __syncthreads();
    }
    if (i < n) rowstart[i] = s[tid] - v;      // exclusive
    if (tid == 255) bsum[blockIdx.x] = s[255];
}

__global__ __launch_bounds__(256) void k_scan2(int* __restrict__ bsum, int nb) {
    __shared__ int s[256];
    int tid = threadIdx.x;
    int v = (tid < nb) ? bsum[tid] : 0;
    s[tid] = v;
    __syncthreads();
    for (int off = 1; off < 256; off <<= 1) {
        int t = (tid >= off) ? s[tid - off] : 0;
        __syncthreads();
        s[tid] += t;
        __syncthreads();
    }
    if (tid < nb) bsum[tid] = s[tid] - v;     // exclusive block offsets
}

__global__ __launch_bounds__(256) void k_scan3(int* __restrict__ rowstart,
                                               const int* __restrict__ bsum,
                                               int n, int total) {
    int i = blockIdx.x * 256 + threadIdx.x;
    if (i < n) rowstart[i] += bsum[blockIdx.x];
    if (i == 0) rowstart[n] = total;
}

__global__ __launch_bounds__(256) void k_copy_int(const int* __restrict__ a,
                                                  int* __restrict__ b, int n) {
    int i = blockIdx.x * 256 + threadIdx.x;
    if (i < n) b[i] = a[i];
}

__global__ __launch_bounds__(256) void k_scatter(const int* __restrict__ srcs,
                                                 const int* __restrict__ dsts,
                                                 const float* __restrict__ dinv,
                                                 int* __restrict__ cursor,
                                                 int* __restrict__ csr_src,
                                                 float* __restrict__ csr_norm, int n) {
    int e = blockIdx.x * 256 + threadIdx.x;
    if (e < n) {
        int s = srcs[e], d = dsts[e];
        int pos = atomicAdd(&cursor[d], 1);
        csr_src[pos]  = s;
        csr_norm[pos] = dinv[s] * dinv[d];
    }
}

// out[r,:] = W[r,:] * ow[(r/128)%3]   (fold order_weights into lin weights)
__global__ __launch_bounds__(256) void k_scale_wlin(const float* __restrict__ W,
                                                    const float* __restrict__ ow,
                                                    float* __restrict__ out, int total) {
    int i = blockIdx.x * 256 + threadIdx.x;
    if (i < total) {
        int row = i >> 8;                 // / 256 cols
        out[i] = W[i] * ow[(row >> 7) % 3];
    }
}

__global__ __launch_bounds__(256) void k_gbounds(const int* __restrict__ batch,
                                                 int* __restrict__ gstart, int n, int g) {
    int i = blockIdx.x * 256 + threadIdx.x;
    if (i >= n) return;
    int b = batch[i];
    if (i == 0) {
        for (int q = 0; q <= b; ++q) gstart[q] = 0;
    } else {
        int bp = batch[i - 1];
        for (int q = bp + 1; q <= b; ++q) gstart[q] = i;
    }
    if (i == n - 1) {
        for (int q = b + 1; q <= g; ++q) gstart[q] = n;
    }
}

// ---------------- CSR gather-aggregation ----------------
// one wave (64 lanes) per node; VEC floats per lane (row width = 64*VEC)
template <int VEC> struct VecT;
template <> struct VecT<4> { using T = float4; };
template <> struct VecT<2> { using T = float2; };

template <int VEC>
__global__ __launch_bounds__(256) void k_agg(const float* __restrict__ H,
                                             const int* __restrict__ rowstart,
                                             const int* __restrict__ csr_src,
                                             const float* __restrict__ csr_norm,
                                             const float* __restrict__ dinv,
                                             const float* __restrict__ bias,
                                             float* __restrict__ out,
                                             int out_stride, int out_off,
                                             int do_relu, int nN) {
    using VT = typename VecT<VEC>::T;
    constexpr int WIDTH = 64 * VEC;
    int n = (blockIdx.x * blockDim.x + threadIdx.x) >> 6;  // global wave id
    int lane = threadIdx.x & 63;
    if (n >= nN) return;

    float di = dinv[n];
    float selfw = di * di;
    float acc[VEC];
    {
        VT v = *reinterpret_cast<const VT*>(H + (size_t)n * WIDTH + lane * VEC);
        const float* vf = reinterpret_cast<const float*>(&v);
#pragma unroll
        for (int j = 0; j < VEC; ++j) acc[j] = vf[j] * selfw;
    }
    int s = rowstart[n], e = rowstart[n + 1];
    int i = s;
    for (; i + 3 < e; i += 4) {
        int s0 = csr_src[i], s1 = csr_src[i + 1], s2 = csr_src[i + 2], s3 = csr_src[i + 3];
        float w0 = csr_norm[i], w1 = csr_norm[i + 1], w2 = csr_norm[i + 2], w3 = csr_norm[i + 3];
        VT v0 = *reinterpret_cast<const VT*>(H + (size_t)s0 * WIDTH + lane * VEC);
        VT v1 = *reinterpret_cast<const VT*>(H + (size_t)s1 * WIDTH + lane * VEC);
        VT v2 = *reinterpret_cast<const VT*>(H + (size_t)s2 * WIDTH + lane * VEC);
        VT v3 = *reinterpret_cast<const VT*>(H + (size_t)s3 * WIDTH + lane * VEC);
        const float* f0 = reinterpret_cast<const float*>(&v0);
        const float* f1 = reinterpret_cast<const float*>(&v1);
        const float* f2 = reinterpret_cast<const float*>(&v2);
        const float* f3 = reinterpret_cast<const float*>(&v3);
#pragma unroll
        for (int j = 0; j < VEC; ++j)
            acc[j] += f0[j] * w0 + f1[j] * w1 + f2[j] * w2 + f3[j] * w3;
    }
    for (; i < e; ++i) {
        int ss = csr_src[i];
        float w = csr_norm[i];
        VT v = *reinterpret_cast<const VT*>(H + (size_t)ss * WIDTH + lane * VEC);
        const float* vf = reinterpret_cast<const float*>(&v);
#pragma unroll
        for (int j = 0; j < VEC; ++j) acc[j] += vf[j] * w;
    }
    if (bias) {
#pragma unroll
        for (int j = 0; j < VEC; ++j) acc[j] += bias[lane * VEC + j];
    }
    if (do_relu) {
#pragma unroll
        for (int j = 0; j < VEC; ++j) acc[j] = fmaxf(acc[j], 0.0f);
    }
    VT o;
    float* of = reinterpret_cast<float*>(&o);
#pragma unroll
    for (int j = 0; j < VEC; ++j) of[j] = acc[j];
    *reinterpret_cast<VT*>(out + (size_t)n * out_stride + out_off + lane * VEC) = o;
}

// ---------------- fp32 tiled GEMM ----------------
// C[m, n0+n] = sum_k A[m,k] * W[k,n]  (+bias, optional relu)
// LAYOUT 0: A row-major with lda.  LAYOUT 1: A in planes of 128:
//           A[m,k] = A[(k>>7)*planeStride + m*128 + (k&127)]
template <int LAYOUT>
__global__ __launch_bounds__(256) void k_gemm(const float* __restrict__ A, int ldaOrPlane,
                                              const float* __restrict__ W,
                                              const float* __restrict__ bias,
                                              float* __restrict__ out,
                                              int out_stride, int out_off,
                                              int nRows, int K, int do_relu) {
    __shared__ float As[16 * 132];  // [k][m], padded to 132
    __shared__ float Ws[16 * 64];   // [k][n]
    int tid = threadIdx.x;
    int m0 = blockIdx.x * 128;
    int n0 = blockIdx.y * 64;
    int tx = tid & 15;   // n group (4 cols)
    int ty = tid >> 4;   // m group (8 rows)

    float acc[8][4];
#pragma unroll
    for (int i = 0; i < 8; ++i)
#pragma unroll
        for (int j = 0; j < 4; ++j) acc[i][j] = 0.0f;

    int nTiles = K >> 4;
    for (int t = 0; t < nTiles; ++t) {
        int k0 = t << 4;
        const float* Atile;
        int alda;
        if (LAYOUT == 0) {
            Atile = A + k0;
            alda = ldaOrPlane;
        } else {
            Atile = A + (size_t)(k0 >> 7) * ldaOrPlane + (k0 & 127);
            alda = 128;
        }
        // load A tile: 128 rows x 16 k = 512 float4s
#pragma unroll
        for (int p = 0; p < 2; ++p) {
            int idx = tid + p * 256;
            int r = idx >> 2;
            int kk4 = idx & 3;
            float4 v = make_float4(0.f, 0.f, 0.f, 0.f);
            if (m0 + r < nRows)
                v = *reinterpret_cast<const float4*>(Atile + (size_t)(m0 + r) * alda + kk4 * 4);
            As[(kk4 * 4 + 0) * 132 + r] = v.x;
            As[(kk4 * 4 + 1) * 132 + r] = v.y;
            As[(kk4 * 4 + 2) * 132 + r] = v.z;
            As[(kk4 * 4 + 3) * 132 + r] = v.w;
        }
        // load W tile: 16 k x 64 n = 256 float4s
        {
            int kk = tid >> 4;
            int nn4 = tid & 15;
            float4 v = *reinterpret_cast<const float4*>(W + (size_t)(k0 + kk) * 256 + n0 + nn4 * 4);
            *reinterpret_cast<float4*>(Ws + kk * 64 + nn4 * 4) = v;
        }
        __syncthreads();
#pragma unroll
        for (int kk = 0; kk < 16; ++kk) {
            float4 a0 = *reinterpret_cast<const float4*>(As + kk * 132 + ty * 8);
            float4 a1 = *reinterpret_cast<const float4*>(As + kk * 132 + ty * 8 + 4);
            float4 w  = *reinterpret_cast<const float4*>(Ws + kk * 64 + tx * 4);
            float av[8] = {a0.x, a0.y, a0.z, a0.w, a1.x, a1.y, a1.z, a1.w};
            float wv[4] = {w.x, w.y, w.z, w.w};
#pragma unroll
            for (int i = 0; i < 8; ++i)
#pragma unroll
                for (int j = 0; j < 4; ++j) acc[i][j] += av[i] * wv[j];
        }
        __syncthreads();
    }
    float bv[4] = {0.f, 0.f, 0.f, 0.f};
    if (bias) {
#pragma unroll
        for (int j = 0; j < 4; ++j) bv[j] = bias[n0 + tx * 4 + j];
    }
#pragma unroll
    for (int i = 0; i < 8; ++i) {
        int gm = m0 + ty * 8 + i;
        if (gm < nRows) {
            float4 v;
            float r0 = acc[i][0] + bv[0];
            float r1 = acc[i][1] + bv[1];
            float r2 = acc[i][2] + bv[2];
            float r3 = acc[i][3] + bv[3];
            if (do_relu) {
                r0 = fmaxf(r0, 0.f); r1 = fmaxf(r1, 0.f);
                r2 = fmaxf(r2, 0.f); r3 = fmaxf(r3, 0.f);
            }
            v.x = r0; v.y = r1; v.z = r2; v.w = r3;
            *reinterpret_cast<float4*>(out + (size_t)gm * out_stride + out_off + n0 + tx * 4) = v;
        }
    }
}

// ---------------- pooling + final FC ----------------

__global__ __launch_bounds__(256) void k_pool(const float* __restrict__ Cfin,
                                              const int* __restrict__ gstart,
                                              float* __restrict__ pooled) {
    int g = blockIdx.x;
    int f = threadIdx.x;
    float acc = 0.0f;
    int s = gstart[g], e = gstart[g + 1];
    for (int n = s; n < e; ++n) acc += Cfin[(size_t)n * 512 + f];
    pooled[g * 256 + f] = acc;
}

__global__ __launch_bounds__(64) void k_fc(const float* __restrict__ pooled,
                                           const float* __restrict__ Wfc,
                                           const float* __restrict__ bfc,
                                           float* __restrict__ outp) {
    __shared__ float h[256];
    int g = blockIdx.x;
    for (int k = threadIdx.x; k < 256; k += 64) h[k] = pooled[g * 256 + k];
    __syncthreads();
    int c = threadIdx.x;
    if (c < CC) {
        float a = bfc[c];
        for (int k = 0; k < 256; ++k) a += h[k] * Wfc[k * CC + c];
        outp[g * CC + c] = a;
    }
}

// ---------------- launch ----------------

extern "C" void kernel_launch(void* const* d_in, const int* in_sizes, int n_in,
                              void* d_out, int out_size, void* d_ws, size_t ws_size,
                              hipStream_t stream) {
    const float* x         = (const float*)d_in[0];
    const int*   edge      = (const int*)d_in[1];   // [2][E]
    const float* diff_feat = (const float*)d_in[2]; // [13][N][128]
    const int*   batch     = (const int*)d_in[3];
    const float* W_conv0 = (const float*)d_in[4];
    const float* b_conv0 = (const float*)d_in[5];
    const float* W_lin0  = (const float*)d_in[6];
    const float* b_lin0  = (const float*)d_in[7];
    const float* W_conv1 = (const float*)d_in[8];
    const float* b_conv1 = (const float*)d_in[9];
    const float* W_lin1  = (const float*)d_in[10];
    const float* b_lin1  = (const float*)d_in[11];
    const float* W_conv2 = (const float*)d_in[12];
    const float* b_conv2 = (const float*)d_in[13];
    const float* W_lin2  = (const float*)d_in[14];
    const float* b_lin2  = (const float*)d_in[15];
    const float* order_w = (const float*)d_in[16];
    const float* W_cls   = (const float*)d_in[17];
    const float* b_cls   = (const float*)d_in[18];
    const float* W_fc    = (const float*)d_in[19];
    const float* b_fc    = (const float*)d_in[20];
    float* outp = (float*)d_out;

    const int* esrc = edge;
    const int* edst = edge + EE;

    // ---- workspace carve-up (~170 MB) with hard size guard ----
    char* w = (char*)d_ws;
    size_t off = 0;
    auto alloc = [&](size_t bytes) {
        void* p = w + off;
        off = (off + bytes + 255) & ~(size_t)255;
        return p;
    };
    float* comb     = (float*)alloc((size_t)NN * 512 * 4);  // [N][512] lin|conv
    float* Bbuf     = (float*)alloc((size_t)NN * 256 * 4);  // matmul out pre-agg
    float* Tbuf     = Bbuf;                                 // agg(x): layer-0 only, aliases Bbuf
    int*   csr_src  = (int*)alloc((size_t)EE * 4);
    float* csr_norm = (float*)alloc((size_t)EE * 4);
    int*   degi     = (int*)alloc((size_t)NN * 4);
    float* dinv     = (float*)alloc((size_t)NN * 4);
    int*   rowstart = (int*)alloc((size_t)(NN + 1) * 4);
    int*   cursor   = (int*)alloc((size_t)NN * 4);
    int*   bsum     = (int*)alloc(256 * 4);
    float* wlin1s   = (float*)alloc((size_t)384 * 256 * 4);
    float* wlin2s   = (float*)alloc((size_t)1152 * 256 * 4);
    int*   gstart   = (int*)alloc((size_t)(GG + 1) * 4);
    float* pooled   = (float*)alloc((size_t)GG * 256 * 4);
    (void)n_in; (void)in_sizes;

    // DIAGNOSTIC GUARD: if the harness workspace is smaller than our layout,
    // do NOT touch it (would fault the GPU). Emit zeros -> "incorrect", which
    // tells us ws_size was the container-killer; next round restructures.
    if (ws_size < off) {
        k_zero_out<<<(out_size + 255) / 256, 256, 0, stream>>>(outp, out_size);
        return;
    }

    const int NB_N = (NN + 255) / 256;   // 196
    const int NB_E = (EE + 255) / 256;   // 6250

    // ---- graph preprocessing ----
    k_fill_int<<<NB_N, 256, 0, stream>>>(degi, 1, NN);
    k_count<<<NB_E, 256, 0, stream>>>(edst, degi, EE);
    k_dinv<<<NB_N, 256, 0, stream>>>(degi, dinv, NN);
    k_scan1<<<NB_N, 256, 0, stream>>>(degi, rowstart, bsum, NN);
    k_scan2<<<1, 256, 0, stream>>>(bsum, NB_N);
    k_scan3<<<NB_N, 256, 0, stream>>>(rowstart, bsum, NN, EE);
    k_copy_int<<<NB_N, 256, 0, stream>>>(rowstart, cursor, NN);
    k_scatter<<<NB_E, 256, 0, stream>>>(esrc, edst, dinv, cursor, csr_src, csr_norm, EE);
    k_scale_wlin<<<(384 * 256) / 256, 256, 0, stream>>>(W_lin1, order_w, wlin1s, 384 * 256);
    k_scale_wlin<<<(1152 * 256) / 256, 256, 0, stream>>>(W_lin2, order_w, wlin2s, 1152 * 256);
    k_gbounds<<<NB_N, 256, 0, stream>>>(batch, gstart, NN, GG);

    dim3 gemm_grid((NN + 127) / 128, 4);
    const int AGG_BLOCKS = (NN * 64 + 255) / 256;  // one wave per node

    // ---- layer 0 ----
    // T = agg(x)  (aggregate-before-matmul: agg commutes with @W)
    k_agg<2><<<AGG_BLOCKS, 256, 0, stream>>>(x, rowstart, csr_src, csr_norm, dinv,
                                             nullptr, Tbuf, 128, 0, 0, NN);
    // comb[:,256:] = relu(T @ W_conv0 + b_conv0)
    k_gemm<0><<<gemm_grid, 256, 0, stream>>>(Tbuf, 128, W_conv0, b_conv0,
                                             comb, 512, 256, NN, 128, 1);
    // comb[:,0:256] = relu(diff_feat[0] @ W_lin0 + b_lin0)
    k_gemm<0><<<gemm_grid, 256, 0, stream>>>(diff_feat, 128, W_lin0, b_lin0,
                                             comb, 512, 0, NN, 128, 1);

    // ---- layer 1 ----
    k_gemm<0><<<gemm_grid, 256, 0, stream>>>(comb, 512, W_conv1, nullptr,
                                             Bbuf, 256, 0, NN, 512, 0);
    k_agg<4><<<AGG_BLOCKS, 256, 0, stream>>>(Bbuf, rowstart, csr_src, csr_norm, dinv,
                                             b_conv1, comb, 512, 256, 1, NN);
    k_gemm<1><<<gemm_grid, 256, 0, stream>>>(diff_feat + (size_t)NN * 128, NN * 128,
                                             wlin1s, b_lin1, comb, 512, 0, NN, 384, 1);

    // ---- layer 2 ----
    k_gemm<0><<<gemm_grid, 256, 0, stream>>>(comb, 512, W_conv2, nullptr,
                                             Bbuf, 256, 0, NN, 512, 0);
    k_agg<4><<<AGG_BLOCKS, 256, 0, stream>>>(Bbuf, rowstart, csr_src, csr_norm, dinv,
                                             b_conv2, comb, 512, 256, 1, NN);
    k_gemm<1><<<gemm_grid, 256, 0, stream>>>(diff_feat + (size_t)4 * NN * 128, NN * 128,
                                             wlin2s, b_lin2, comb, 512, 0, NN, 1152, 1);

    // ---- classifier GCN (no relu) ----
    k_gemm<0><<<gemm_grid, 256, 0, stream>>>(comb, 512, W_cls, nullptr,
                                             Bbuf, 256, 0, NN, 512, 0);
    k_agg<4><<<AGG_BLOCKS, 256, 0, stream>>>(Bbuf, rowstart, csr_src, csr_norm, dinv,
                                             b_cls, comb, 512, 0, 0, NN);

    // ---- pool + FC ----
    k_pool<<<GG, 256, 0, stream>>>(comb, gstart, pooled);
    k_fc<<<GG, 64, 0, stream>>>(pooled, W_fc, b_fc, outp);
}

// Round 4
// 2166.542 us; speedup vs baseline: 1.2053x; 1.2053x over previous
//
#include <hip/hip_runtime.h>

// ---------------- problem constants ----------------
namespace {
constexpr int NN  = 50000;    // nodes
constexpr int EE  = 1600000;  // edges
constexpr int GG  = 512;      // graphs
constexpr int CC  = 10;       // classes
}

typedef __attribute__((ext_vector_type(8))) short bf16x8;
typedef __attribute__((ext_vector_type(4))) float f32x4;

__device__ inline unsigned short bf16_rtn(float f) {
    unsigned u = __float_as_uint(f);
    unsigned r = (u + 0x7FFF + ((u >> 16) & 1)) >> 16;
    return (unsigned short)r;
}
__device__ inline float bf16_to_f(unsigned short s) {
    return __uint_as_float(((unsigned)s) << 16);
}

// ---------------- small utility kernels ----------------

__global__ __launch_bounds__(256) void k_zero_out(float* p, int n) {
    int i = blockIdx.x * 256 + threadIdx.x;
    if (i < n) p[i] = 0.0f;
}

__global__ __launch_bounds__(256) void k_fill_int(int* p, int val, int n) {
    int i = blockIdx.x * 256 + threadIdx.x;
    if (i < n) p[i] = val;
}

__global__ __launch_bounds__(256) void k_count(const int* __restrict__ dst,
                                               int* __restrict__ deg, int n) {
    int i = blockIdx.x * 256 + threadIdx.x;
    if (i < n) atomicAdd(&deg[dst[i]], 1);
}

__global__ __launch_bounds__(256) void k_dinv(const int* __restrict__ deg,
                                              float* __restrict__ dinv, int n) {
    int i = blockIdx.x * 256 + threadIdx.x;
    if (i < n) dinv[i] = 1.0f / sqrtf((float)deg[i]);
}

__global__ __launch_bounds__(256) void k_scan1(const int* __restrict__ deg,
                                               int* __restrict__ rowstart,
                                               int* __restrict__ bsum, int n) {
    __shared__ int s[256];
    int tid = threadIdx.x;
    int i = blockIdx.x * 256 + tid;
    int v = (i < n) ? (deg[i] - 1) : 0;
    s[tid] = v;
    __syncthreads();
    for (int off = 1; off < 256; off <<= 1) {
        int t = (tid >= off) ? s[tid - off] : 0;
        __syncthreads();
        s[tid] += t;
        __syncthreads();
    }
    if (i < n) rowstart[i] = s[tid] - v;
    if (tid == 255) bsum[blockIdx.x] = s[255];
}

__global__ __launch_bounds__(256) void k_scan2(int* __restrict__ bsum, int nb) {
    __shared__ int s[256];
    int tid = threadIdx.x;
    int v = (tid < nb) ? bsum[tid] : 0;
    s[tid] = v;
    __syncthreads();
    for (int off = 1; off < 256; off <<= 1) {
        int t = (tid >= off) ? s[tid - off] : 0;
        __syncthreads();
        s[tid] += t;
        __syncthreads();
    }
    if (tid < nb) bsum[tid] = s[tid] - v;
}

__global__ __launch_bounds__(256) void k_scan3(int* __restrict__ rowstart,
                                               const int* __restrict__ bsum,
                                               int n, int total) {
    int i = blockIdx.x * 256 + threadIdx.x;
    if (i < n) rowstart[i] += bsum[blockIdx.x];
    if (i == 0) rowstart[n] = total;
}

__global__ __launch_bounds__(256) void k_copy_int(const int* __restrict__ a,
                                                  int* __restrict__ b, int n) {
    int i = blockIdx.x * 256 + threadIdx.x;
    if (i < n) b[i] = a[i];
}

__global__ __launch_bounds__(256) void k_scatter(const int* __restrict__ srcs,
                                                 const int* __restrict__ dsts,
                                                 const float* __restrict__ dinv,
                                                 int* __restrict__ cursor,
                                                 int* __restrict__ csr_src,
                                                 float* __restrict__ csr_norm, int n) {
    int e = blockIdx.x * 256 + threadIdx.x;
    if (e < n) {
        int s = srcs[e], d = dsts[e];
        int pos = atomicAdd(&cursor[d], 1);
        csr_src[pos]  = s;
        csr_norm[pos] = dinv[s] * dinv[d];
    }
}

// W: [K][256] fp32 -> Wt hi/lo: [256][K] bf16 (k-contiguous), optional ow-fold
__global__ __launch_bounds__(256) void k_prep_w(const float* __restrict__ W,
                                                const float* __restrict__ ow,
                                                int K, int useOw,
                                                short* __restrict__ hi,
                                                short* __restrict__ lo) {
    int k = blockIdx.x * 256 + threadIdx.x;
    int n = blockIdx.y;
    if (k >= K) return;
    float a = W[(size_t)k * 256 + n];
    if (useOw) a *= ow[(k >> 7) % 3];
    unsigned short h = bf16_rtn(a);
    unsigned short l = bf16_rtn(a - bf16_to_f(h));
    hi[(size_t)n * K + k] = (short)h;
    lo[(size_t)n * K + k] = (short)l;
}

__global__ __launch_bounds__(256) void k_gbounds(const int* __restrict__ batch,
                                                 int* __restrict__ gstart, int n, int g) {
    int i = blockIdx.x * 256 + threadIdx.x;
    if (i >= n) return;
    int b = batch[i];
    if (i == 0) {
        for (int q = 0; q <= b; ++q) gstart[q] = 0;
    } else {
        int bp = batch[i - 1];
        for (int q = bp + 1; q <= b; ++q) gstart[q] = i;
    }
    if (i == n - 1) {
        for (int q = b + 1; q <= g; ++q) gstart[q] = n;
    }
}

// ---------------- CSR gather-aggregation (unchanged fp32) ----------------
template <int VEC> struct VecT;
template <> struct VecT<4> { using T = float4; };
template <> struct VecT<2> { using T = float2; };

template <int VEC>
__global__ __launch_bounds__(256) void k_agg(const float* __restrict__ H,
                                             const int* __restrict__ rowstart,
                                             const int* __restrict__ csr_src,
                                             const float* __restrict__ csr_norm,
                                             const float* __restrict__ dinv,
                                             const float* __restrict__ bias,
                                             float* __restrict__ out,
                                             int out_stride, int out_off,
                                             int do_relu, int nN) {
    using VT = typename VecT<VEC>::T;
    constexpr int WIDTH = 64 * VEC;
    int n = (blockIdx.x * blockDim.x + threadIdx.x) >> 6;
    int lane = threadIdx.x & 63;
    if (n >= nN) return;

    float di = dinv[n];
    float selfw = di * di;
    float acc[VEC];
    {
        VT v = *reinterpret_cast<const VT*>(H + (size_t)n * WIDTH + lane * VEC);
        const float* vf = reinterpret_cast<const float*>(&v);
#pragma unroll
        for (int j = 0; j < VEC; ++j) acc[j] = vf[j] * selfw;
    }
    int s = rowstart[n], e = rowstart[n + 1];
    int i = s;
    for (; i + 3 < e; i += 4) {
        int s0 = csr_src[i], s1 = csr_src[i + 1], s2 = csr_src[i + 2], s3 = csr_src[i + 3];
        float w0 = csr_norm[i], w1 = csr_norm[i + 1], w2 = csr_norm[i + 2], w3 = csr_norm[i + 3];
        VT v0 = *reinterpret_cast<const VT*>(H + (size_t)s0 * WIDTH + lane * VEC);
        VT v1 = *reinterpret_cast<const VT*>(H + (size_t)s1 * WIDTH + lane * VEC);
        VT v2 = *reinterpret_cast<const VT*>(H + (size_t)s2 * WIDTH + lane * VEC);
        VT v3 = *reinterpret_cast<const VT*>(H + (size_t)s3 * WIDTH + lane * VEC);
        const float* f0 = reinterpret_cast<const float*>(&v0);
        const float* f1 = reinterpret_cast<const float*>(&v1);
        const float* f2 = reinterpret_cast<const float*>(&v2);
        const float* f3 = reinterpret_cast<const float*>(&v3);
#pragma unroll
        for (int j = 0; j < VEC; ++j)
            acc[j] += f0[j] * w0 + f1[j] * w1 + f2[j] * w2 + f3[j] * w3;
    }
    for (; i < e; ++i) {
        int ss = csr_src[i];
        float w = csr_norm[i];
        VT v = *reinterpret_cast<const VT*>(H + (size_t)ss * WIDTH + lane * VEC);
        const float* vf = reinterpret_cast<const float*>(&v);
#pragma unroll
        for (int j = 0; j < VEC; ++j) acc[j] += vf[j] * w;
    }
    if (bias) {
#pragma unroll
        for (int j = 0; j < VEC; ++j) acc[j] += bias[lane * VEC + j];
    }
    if (do_relu) {
#pragma unroll
        for (int j = 0; j < VEC; ++j) acc[j] = fmaxf(acc[j], 0.0f);
    }
    VT o;
    float* of = reinterpret_cast<float*>(&o);
#pragma unroll
    for (int j = 0; j < VEC; ++j) of[j] = acc[j];
    *reinterpret_cast<VT*>(out + (size_t)n * out_stride + out_off + lane * VEC) = o;
}

// ---------------- bf16x3-split MFMA GEMM ----------------
// C[m, n0+n] = sum_k A[m,k]*W[k,n] (+bias, relu). A fp32; W pre-split bf16 hi/lo,
// pre-transposed [256][K] k-contiguous. A converted fp32->bf16 hi/lo in staging.
// BM=128, BN=128, BK=32; 256 threads = 4 waves (2x2), wave tile 64x64.
// LAYOUT 0: A row-major lda. LAYOUT 1: A planes of 128 (diff_feat).
template <int LAYOUT>
__global__ __launch_bounds__(256) void k_gemm_mfma(
    const float* __restrict__ A, int ldaOrPlane,
    const short* __restrict__ Bh, const short* __restrict__ Bl,
    const float* __restrict__ bias,
    float* __restrict__ out, int out_stride, int out_off,
    int nRows, int K, int do_relu)
{
    // padded stride 40 shorts (80 B): 16B-aligned, ~2-way banks on b128 frag reads
    __shared__ short Ah[128 * 40];
    __shared__ short Al[128 * 40];
    __shared__ short Bhs[128 * 40];
    __shared__ short Bls[128 * 40];

    int tid  = threadIdx.x;
    int m0   = blockIdx.x * 128;
    int n0   = blockIdx.y * 128;
    int lane = tid & 63;
    int w    = tid >> 6;
    int wr   = w >> 1, wc = w & 1;
    int lrow = lane & 15;   // frag row/col
    int lkb  = lane >> 4;   // frag k-chunk (8 elems)

    f32x4 acc[4][4];
#pragma unroll
    for (int i = 0; i < 4; ++i)
#pragma unroll
        for (int j = 0; j < 4; ++j) {
            acc[i][j].x = 0.f; acc[i][j].y = 0.f;
            acc[i][j].z = 0.f; acc[i][j].w = 0.f;
        }

    int nSteps = K >> 5;
    for (int kt = 0; kt < nSteps; ++kt) {
        int k0 = kt << 5;
        const float* Ag;
        int alda;
        if (LAYOUT == 0) { Ag = A + k0; alda = ldaOrPlane; }
        else { Ag = A + (size_t)(k0 >> 7) * ldaOrPlane + (k0 & 127); alda = 128; }

        // ---- stage A: 128x32 fp32 -> bf16 hi/lo (4 passes x 256 thr x float4) ----
#pragma unroll
        for (int p = 0; p < 4; ++p) {
            int idx = p * 256 + tid;    // 0..1023
            int r   = idx >> 3;         // row 0..127
            int kq  = idx & 7;          // float4 within row
            float4 v = make_float4(0.f, 0.f, 0.f, 0.f);
            if (m0 + r < nRows)
                v = *reinterpret_cast<const float4*>(Ag + (size_t)(m0 + r) * alda + kq * 4);
            unsigned short h0 = bf16_rtn(v.x), h1 = bf16_rtn(v.y),
                           h2 = bf16_rtn(v.z), h3 = bf16_rtn(v.w);
            unsigned short l0 = bf16_rtn(v.x - bf16_to_f(h0)),
                           l1 = bf16_rtn(v.y - bf16_to_f(h1)),
                           l2 = bf16_rtn(v.z - bf16_to_f(h2)),
                           l3 = bf16_rtn(v.w - bf16_to_f(h3));
            uint2 hp, lp;
            hp.x = (unsigned)h0 | ((unsigned)h1 << 16);
            hp.y = (unsigned)h2 | ((unsigned)h3 << 16);
            lp.x = (unsigned)l0 | ((unsigned)l1 << 16);
            lp.y = (unsigned)l2 | ((unsigned)l3 << 16);
            *reinterpret_cast<uint2*>(&Ah[r * 40 + kq * 4]) = hp;
            *reinterpret_cast<uint2*>(&Al[r * 40 + kq * 4]) = lp;
        }
        // ---- stage B: [n][k] bf16 hi/lo, 128x32 each (2 passes x bf16x8) ----
#pragma unroll
        for (int p = 0; p < 2; ++p) {
            int idx = p * 256 + tid;    // 0..511
            int n   = idx >> 2;         // 0..127
            int kq  = idx & 3;          // 8-short chunk
            size_t g = (size_t)(n0 + n) * K + k0 + kq * 8;
            *reinterpret_cast<bf16x8*>(&Bhs[n * 40 + kq * 8]) =
                *reinterpret_cast<const bf16x8*>(&Bh[g]);
            *reinterpret_cast<bf16x8*>(&Bls[n * 40 + kq * 8]) =
                *reinterpret_cast<const bf16x8*>(&Bl[g]);
        }
        __syncthreads();

        bf16x8 afh[4], afl[4], bfh[4], bfl[4];
#pragma unroll
        for (int f = 0; f < 4; ++f) {
            int ar = wr * 64 + f * 16 + lrow;
            afh[f] = *reinterpret_cast<const bf16x8*>(&Ah[ar * 40 + lkb * 8]);
            afl[f] = *reinterpret_cast<const bf16x8*>(&Al[ar * 40 + lkb * 8]);
            int br = wc * 64 + f * 16 + lrow;
            bfh[f] = *reinterpret_cast<const bf16x8*>(&Bhs[br * 40 + lkb * 8]);
            bfl[f] = *reinterpret_cast<const bf16x8*>(&Bls[br * 40 + lkb * 8]);
        }
#pragma unroll
        for (int i = 0; i < 4; ++i)
#pragma unroll
            for (int j = 0; j < 4; ++j) {
                acc[i][j] = __builtin_amdgcn_mfma_f32_16x16x32_bf16(afh[i], bfh[j], acc[i][j], 0, 0, 0);
                acc[i][j] = __builtin_amdgcn_mfma_f32_16x16x32_bf16(afh[i], bfl[j], acc[i][j], 0, 0, 0);
                acc[i][j] = __builtin_amdgcn_mfma_f32_16x16x32_bf16(afl[i], bfh[j], acc[i][j], 0, 0, 0);
            }
        __syncthreads();
    }

    // ---- epilogue: C/D layout col=lane&15, row=(lane>>4)*4+r (m89-verified) ----
#pragma unroll
    for (int j = 0; j < 4; ++j) {
        int col = n0 + wc * 64 + j * 16 + lrow;
        float bv = bias ? bias[col] : 0.0f;
#pragma unroll
        for (int i = 0; i < 4; ++i) {
#pragma unroll
            for (int r = 0; r < 4; ++r) {
                int m = m0 + wr * 64 + i * 16 + lkb * 4 + r;
                if (m < nRows) {
                    float v = acc[i][j][r] + bv;
                    if (do_relu) v = fmaxf(v, 0.0f);
                    out[(size_t)m * out_stride + out_off + col] = v;
                }
            }
        }
    }
}

// ---------------- pooling + final FC ----------------

__global__ __launch_bounds__(256) void k_pool(const float* __restrict__ Cfin,
                                              const int* __restrict__ gstart,
                                              float* __restrict__ pooled) {
    int g = blockIdx.x;
    int f = threadIdx.x;
    float acc = 0.0f;
    int s = gstart[g], e = gstart[g + 1];
    for (int n = s; n < e; ++n) acc += Cfin[(size_t)n * 512 + f];
    pooled[g * 256 + f] = acc;
}

__global__ __launch_bounds__(64) void k_fc(const float* __restrict__ pooled,
                                           const float* __restrict__ Wfc,
                                           const float* __restrict__ bfc,
                                           float* __restrict__ outp) {
    __shared__ float h[256];
    int g = blockIdx.x;
    for (int k = threadIdx.x; k < 256; k += 64) h[k] = pooled[g * 256 + k];
    __syncthreads();
    int c = threadIdx.x;
    if (c < CC) {
        float a = bfc[c];
        for (int k = 0; k < 256; ++k) a += h[k] * Wfc[k * CC + c];
        outp[g * CC + c] = a;
    }
}

// ---------------- launch ----------------

extern "C" void kernel_launch(void* const* d_in, const int* in_sizes, int n_in,
                              void* d_out, int out_size, void* d_ws, size_t ws_size,
                              hipStream_t stream) {
    const float* x         = (const float*)d_in[0];
    const int*   edge      = (const int*)d_in[1];
    const float* diff_feat = (const float*)d_in[2];
    const int*   batch     = (const int*)d_in[3];
    const float* W_conv0 = (const float*)d_in[4];
    const float* b_conv0 = (const float*)d_in[5];
    const float* W_lin0  = (const float*)d_in[6];
    const float* b_lin0  = (const float*)d_in[7];
    const float* W_conv1 = (const float*)d_in[8];
    const float* b_conv1 = (const float*)d_in[9];
    const float* W_lin1  = (const float*)d_in[10];
    const float* b_lin1  = (const float*)d_in[11];
    const float* W_conv2 = (const float*)d_in[12];
    const float* b_conv2 = (const float*)d_in[13];
    const float* W_lin2  = (const float*)d_in[14];
    const float* b_lin2  = (const float*)d_in[15];
    const float* order_w = (const float*)d_in[16];
    const float* W_cls   = (const float*)d_in[17];
    const float* b_cls   = (const float*)d_in[18];
    const float* W_fc    = (const float*)d_in[19];
    const float* b_fc    = (const float*)d_in[20];
    float* outp = (float*)d_out;

    const int* esrc = edge;
    const int* edst = edge + EE;

    // ---- workspace carve-up with hard size guard ----
    char* w = (char*)d_ws;
    size_t off = 0;
    auto alloc = [&](size_t bytes) {
        void* p = w + off;
        off = (off + bytes + 255) & ~(size_t)255;
        return p;
    };
    float* comb     = (float*)alloc((size_t)NN * 512 * 4);
    float* Bbuf     = (float*)alloc((size_t)NN * 256 * 4);
    float* Tbuf     = Bbuf;  // layer-0 only, aliases Bbuf
    int*   csr_src  = (int*)alloc((size_t)EE * 4);
    float* csr_norm = (float*)alloc((size_t)EE * 4);
    int*   degi     = (int*)alloc((size_t)NN * 4);
    float* dinv     = (float*)alloc((size_t)NN * 4);
    int*   rowstart = (int*)alloc((size_t)(NN + 1) * 4);
    int*   cursor   = (int*)alloc((size_t)NN * 4);
    int*   bsum     = (int*)alloc(256 * 4);
    // pre-split transposed weights (bf16 hi/lo, [256][K])
    short* wt0h  = (short*)alloc((size_t)256 * 128 * 2);
    short* wt0l  = (short*)alloc((size_t)256 * 128 * 2);
    short* wl0h  = (short*)alloc((size_t)256 * 128 * 2);
    short* wl0l  = (short*)alloc((size_t)256 * 128 * 2);
    short* wt1h  = (short*)alloc((size_t)256 * 512 * 2);
    short* wt1l  = (short*)alloc((size_t)256 * 512 * 2);
    short* wl1h  = (short*)alloc((size_t)256 * 384 * 2);
    short* wl1l  = (short*)alloc((size_t)256 * 384 * 2);
    short* wt2h  = (short*)alloc((size_t)256 * 512 * 2);
    short* wt2l  = (short*)alloc((size_t)256 * 512 * 2);
    short* wl2h  = (short*)alloc((size_t)256 * 1152 * 2);
    short* wl2l  = (short*)alloc((size_t)256 * 1152 * 2);
    short* wch   = (short*)alloc((size_t)256 * 512 * 2);
    short* wcl   = (short*)alloc((size_t)256 * 512 * 2);
    int*   gstart = (int*)alloc((size_t)(GG + 1) * 4);
    float* pooled = (float*)alloc((size_t)GG * 256 * 4);
    (void)n_in; (void)in_sizes;

    if (ws_size < off) {  // diagnostic guard: never fault the GPU
        k_zero_out<<<(out_size + 255) / 256, 256, 0, stream>>>(outp, out_size);
        return;
    }

    const int NB_N = (NN + 255) / 256;
    const int NB_E = (EE + 255) / 256;

    // ---- graph preprocessing ----
    k_fill_int<<<NB_N, 256, 0, stream>>>(degi, 1, NN);
    k_count<<<NB_E, 256, 0, stream>>>(edst, degi, EE);
    k_dinv<<<NB_N, 256, 0, stream>>>(degi, dinv, NN);
    k_scan1<<<NB_N, 256, 0, stream>>>(degi, rowstart, bsum, NN);
    k_scan2<<<1, 256, 0, stream>>>(bsum, NB_N);
    k_scan3<<<NB_N, 256, 0, stream>>>(rowstart, bsum, NN, EE);
    k_copy_int<<<NB_N, 256, 0, stream>>>(rowstart, cursor, NN);
    k_scatter<<<NB_E, 256, 0, stream>>>(esrc, edst, dinv, cursor, csr_src, csr_norm, EE);
    k_gbounds<<<NB_N, 256, 0, stream>>>(batch, gstart, NN, GG);

    // ---- weight prep: transpose + bf16 split (+ow fold for lin1/lin2) ----
    k_prep_w<<<dim3(1, 256),  256, 0, stream>>>(W_conv0, order_w, 128,  0, wt0h, wt0l);
    k_prep_w<<<dim3(1, 256),  256, 0, stream>>>(W_lin0,  order_w, 128,  0, wl0h, wl0l);
    k_prep_w<<<dim3(2, 256),  256, 0, stream>>>(W_conv1, order_w, 512,  0, wt1h, wt1l);
    k_prep_w<<<dim3(2, 256),  256, 0, stream>>>(W_lin1,  order_w, 384,  1, wl1h, wl1l);
    k_prep_w<<<dim3(2, 256),  256, 0, stream>>>(W_conv2, order_w, 512,  0, wt2h, wt2l);
    k_prep_w<<<dim3(5, 256),  256, 0, stream>>>(W_lin2,  order_w, 1152, 1, wl2h, wl2l);
    k_prep_w<<<dim3(2, 256),  256, 0, stream>>>(W_cls,   order_w, 512,  0, wch,  wcl);

    dim3 gg((NN + 127) / 128, 2);   // BM=128, BN=128, N=256
    const int AGG_BLOCKS = (NN * 64 + 255) / 256;

    // ---- layer 0 ----
    k_agg<2><<<AGG_BLOCKS, 256, 0, stream>>>(x, rowstart, csr_src, csr_norm, dinv,
                                             nullptr, Tbuf, 128, 0, 0, NN);
    k_gemm_mfma<0><<<gg, 256, 0, stream>>>(Tbuf, 128, wt0h, wt0l, b_conv0,
                                           comb, 512, 256, NN, 128, 1);
    k_gemm_mfma<0><<<gg, 256, 0, stream>>>(diff_feat, 128, wl0h, wl0l, b_lin0,
                                           comb, 512, 0, NN, 128, 1);

    // ---- layer 1 ----
    k_gemm_mfma<0><<<gg, 256, 0, stream>>>(comb, 512, wt1h, wt1l, nullptr,
                                           Bbuf, 256, 0, NN, 512, 0);
    k_agg<4><<<AGG_BLOCKS, 256, 0, stream>>>(Bbuf, rowstart, csr_src, csr_norm, dinv,
                                             b_conv1, comb, 512, 256, 1, NN);
    k_gemm_mfma<1><<<gg, 256, 0, stream>>>(diff_feat + (size_t)NN * 128, NN * 128,
                                           wl1h, wl1l, b_lin1, comb, 512, 0, NN, 384, 1);

    // ---- layer 2 ----
    k_gemm_mfma<0><<<gg, 256, 0, stream>>>(comb, 512, wt2h, wt2l, nullptr,
                                           Bbuf, 256, 0, NN, 512, 0);
    k_agg<4><<<AGG_BLOCKS, 256, 0, stream>>>(Bbuf, rowstart, csr_src, csr_norm, dinv,
                                             b_conv2, comb, 512, 256, 1, NN);
    k_gemm_mfma<1><<<gg, 256, 0, stream>>>(diff_feat + (size_t)4 * NN * 128, NN * 128,
                                           wl2h, wl2l, b_lin2, comb, 512, 0, NN, 1152, 1);

    // ---- classifier GCN ----
    k_gemm_mfma<0><<<gg, 256, 0, stream>>>(comb, 512, wch, wcl, nullptr,
                                           Bbuf, 256, 0, NN, 512, 0);
    k_agg<4><<<AGG_BLOCKS, 256, 0, stream>>>(Bbuf, rowstart, csr_src, csr_norm, dinv,
                                             b_cls, comb, 512, 0, 0, NN);

    // ---- pool + FC ----
    k_pool<<<GG, 256, 0, stream>>>(comb, gstart, pooled);
    k_fc<<<GG, 64, 0, stream>>>(pooled, W_fc, b_fc, outp);
}